// Round 17
// baseline (53.420 us; speedup 1.0000x reference)
//
#include <hip/hip_runtime.h>

// ROIAlign3D: features [B=2,C=128,D=16,H=64,W=64] f32, rois [B,N=64,6] f32
// out [B,N,C,7,7,7] f32. SAMPLING_RATIO=2, ALIGNED=true, SPATIAL_SCALE=1.
//
// Round 17: v15 (39.2us best) + memory-level parallelism + L2 remap:
//  - cell phase: per-z-slot READ BATCHING (16 dwords into regs before math;
//    8 ds_read2 outstanding vs ~2 at v15's VGPR=16).
//  - staging: 2x unroll, 4 global loads in flight before packs.
//  - n-fastest block map: 64 concurrent blocks share one 512KB channel-plane
//    -> staging L2-hits (FETCH_SIZE is the attribution signal).
constexpr int Bc = 2, Nc = 64, Cc = 128, Dc = 16, Hc = 64, Wc = 64;
constexpr int OD = 7, OH = 7, OW = 7;
constexpr int CELLS = OD * OH * OW;          // 343
constexpr int DHW = Dc * Hc * Wc, HW = Hc * Wc;
constexpr int MAXZ = 10, MAXY = 25, MAXX = 25;
constexpr int SUBSZ = MAXZ * MAXY * (MAXX + 1);   // 6500

typedef _Float16 h2f __attribute__((ext_vector_type(2)));

__device__ inline unsigned pk_f16(float a, float b) {
    return __builtin_bit_cast(unsigned, __builtin_amdgcn_cvt_pkrtz(a, b));
}
__device__ inline h2f uh(unsigned u) { return __builtin_bit_cast(h2f, u); }

__global__ __launch_bounds__(384) void roialign3d_v17(
    const float* __restrict__ feat, const float* __restrict__ rois,
    float* __restrict__ out)
{
    __shared__ __align__(16) unsigned sub[SUBSZ + 2];
    __shared__ __align__(16) int2     tzp[14];   // raw z rows (c0,c1)
    __shared__ __align__(16) float2   wzp[14];
    __shared__ __align__(16) int2     typ[14];   // premult xnp
    __shared__ __align__(16) unsigned wyb[28];   // broadcast f16 pairs
    __shared__ __align__(16) unsigned wxb[28];
    __shared__ __align__(16) int      txo[14];

    const int blk = blockIdx.x;
    const int n   = blk & 63;            // n fastest: plane sharing in L2
    const int cp  = (blk >> 6) & 63;
    const int b   = blk >> 12;
    const int tid = threadIdx.x;

    const float* rp = rois + (size_t)(b * Nc + n) * 6;
    float r1a[3] = {rp[0] - 0.5f, rp[1] - 0.5f, rp[2] - 0.5f};
    float r2a[3] = {rp[3] - 0.5f, rp[4] - 0.5f, rp[5] - 0.5f};
    const int dims[3] = {Dc, Hc, Wc};
    const int maxn[3] = {MAXZ, MAXY, MAXX};

    float bs[3]; int lo[3], ncnt[3];
    #pragma unroll
    for (int a = 0; a < 3; ++a) {
        bs[a] = fmaxf(r2a[a] - r1a[a], 1e-6f) * (1.0f / 7.0f);
        float smin = r1a[a] + 0.25f * bs[a];
        float smax = r1a[a] + 6.75f * bs[a];
        int l = max(0, (int)floorf(smin));
        int h = min(dims[a] - 1, (int)floorf(smax) + 1);
        lo[a] = l;
        ncnt[a] = min(h - l + 1, maxn[a]);    // maxn clamp = memory safety only
    }
    const int zn = ncnt[0], yn = ncnt[1], xn = ncnt[2];
    const int xnp = xn | 1;                   // odd stride (coprime w/ 32)
    const int rows = zn * yn;
    const int zstride = yn * xnp;

    // Axis tables (42 threads), packed-f16 broadcast weights for y/x.
    if (tid < 42) {
        int a = tid / 14, m = tid - a * 14;
        float v = r1a[a] + ((float)m + 0.5f) * 0.5f * bs[a];
        float f = floorf(v);
        float l = v - f;
        int i0 = (int)f;
        int d  = dims[a];
        float w0 = (i0 >= 0 && i0 < d) ? 1.0f - l : 0.0f;
        float w1 = (i0 + 1 < d) ? l : 0.0f;
        if (a == 0) {
            int c0 = min(max(i0 - lo[0], 0), zn - 1);
            int c1 = min(max(i0 + 1 - lo[0], 0), zn - 1);
            tzp[m] = make_int2(c0, c1);              // RAW rows
            wzp[m] = make_float2(w0, w1);
        } else if (a == 1) {
            int c0 = min(max(i0 - lo[1], 0), yn - 1);
            int c1 = min(max(i0 + 1 - lo[1], 0), yn - 1);
            typ[m] = make_int2(c0 * xnp, c1 * xnp);
            wyb[2 * m]     = pk_f16(w0, w0);
            wyb[2 * m + 1] = pk_f16(w1, w1);
        } else {
            // pair trick: corners are (c0, c0+1); c0 in [-1, xn-1].
            int c0 = min(max(i0 - lo[2], -1), xn - 1);
            txo[m] = c0;
            wxb[2 * m]     = pk_f16(w0, w0);
            wxb[2 * m + 1] = pk_f16(w1, w1);
        }
    }
    if (tid == 64) sub[0] = 0;                        // front pad (c0 = -1)
    if (tid == 65) sub[1 + rows * xnp] = 0;           // end pad

    // ---- Stage subvolume (fp16x2), 2x unrolled for load overlap. ----
    const int c0ch = cp * 2;
    const float* fb = feat + ((size_t)b * Cc + c0ch) * DHW;
    const unsigned m32x = 0xFFFFFFFFu / (unsigned)xnp + 1u;
    const unsigned m32y = 0xFFFFFFFFu / (unsigned)yn + 1u;
    const int gz = lo[0] * HW + lo[1] * Wc + lo[2];
    const int total = rows * xnp;
    for (int p = tid; p < total; p += 768) {
        int row = (int)__umulhi((unsigned)p, m32x);
        int x   = p - row * xnp;
        int xs  = min(x, xn - 1);
        int z   = (int)__umulhi((unsigned)row, m32y);
        int y   = row - z * yn;
        int g   = gz + (z << 12) + (y << 6) + xs;     // HW=4096, Wc=64
        int p2  = p + 384;
        bool ok2 = p2 < total;
        int p2c = ok2 ? p2 : p;
        int row2 = (int)__umulhi((unsigned)p2c, m32x);
        int x2   = p2c - row2 * xnp;
        int xs2  = min(x2, xn - 1);
        int z2   = (int)__umulhi((unsigned)row2, m32y);
        int y2   = row2 - z2 * yn;
        int g2   = gz + (z2 << 12) + (y2 << 6) + xs2;
        // issue all four loads before any pack/write
        float va0 = fb[g],  vb0 = fb[g + DHW];
        float va1 = fb[g2], vb1 = fb[g2 + DHW];
        sub[1 + p] = pk_f16(va0, vb0);
        if (ok2) sub[1 + p2] = pk_f16(va1, vb1);
    }
    __syncthreads();

    if (tid < CELLS) {
        int i   = tid / 49;
        int rem = tid - i * 49;
        int j   = rem / 7;
        int k   = rem - j * 7;
        int4   tzr  = *(const int4*)&tzp[2 * i];    // (c0,c1,c0',c1') raw
        float4 wzv  = *(const float4*)&wzp[2 * i];
        int4   ty   = *(const int4*)&typ[2 * j];
        uint4  wyb4 = *(const uint4*)&wyb[4 * j];
        uint4  wxb4 = *(const uint4*)&wxb[4 * k];
        int xo0 = txo[2 * k], xo1 = txo[2 * k + 1];

        const unsigned* G = sub + 1;
        h2f wx00 = uh(wxb4.x), wx01 = uh(wxb4.y);
        h2f wx10 = uh(wxb4.z), wx11 = uh(wxb4.w);
        const h2f wys[4] = {uh(wyb4.x), uh(wyb4.y), uh(wyb4.z), uh(wyb4.w)};

        // z 3-slot collapse: corners lie in {c0, c0+1, c0+2}.
        int c0z = tzr.x;
        int p1 = tzr.y - c0z, p2 = tzr.z - c0z, p3 = tzr.w - c0z;
        float cz0 = wzv.x + (p1 == 0 ? wzv.y : 0.0f)
                  + (p2 == 0 ? wzv.z : 0.0f) + (p3 == 0 ? wzv.w : 0.0f);
        float cz1 = (p1 == 1 ? wzv.y : 0.0f)
                  + (p2 == 1 ? wzv.z : 0.0f) + (p3 == 1 ? wzv.w : 0.0f);
        float cz2 = (p3 == 2 ? wzv.w : 0.0f);
        int zb0 = c0z * zstride;
        int zb1 = min(c0z + 1, zn - 1) * zstride;
        int zb2 = min(c0z + 2, zn - 1) * zstride;

        const int   zbs[3] = {zb0, zb1, zb2};
        const float czs[3] = {cz0, cz1, cz2};
        const int   yo[4]  = {ty.x, ty.y, ty.z, ty.w};

        float a0 = 0.0f, a1 = 0.0f;
        #pragma unroll
        for (int d = 0; d < 3; ++d) {
            int zb = zbs[d];
            // batch all 16 dword reads of this z-slot before any math
            unsigned ra[16];
            #pragma unroll
            for (int yi = 0; yi < 4; ++yi) {
                int base = zb + yo[yi];
                ra[4 * yi + 0] = G[base + xo0];
                ra[4 * yi + 1] = G[base + xo0 + 1];
                ra[4 * yi + 2] = G[base + xo1];
                ra[4 * yi + 3] = G[base + xo1 + 1];
            }
            h2f s = {(_Float16)0, (_Float16)0};
            #pragma unroll
            for (int yi = 0; yi < 4; ++yi) {
                h2f xr = uh(ra[4 * yi + 0]) * wx00 + uh(ra[4 * yi + 1]) * wx01
                       + uh(ra[4 * yi + 2]) * wx10 + uh(ra[4 * yi + 3]) * wx11;
                s = s + wys[yi] * xr;
            }
            a0 = fmaf(czs[d], (float)s.x, a0);
            a1 = fmaf(czs[d], (float)s.y, a1);
        }
        size_t obase = ((size_t)(b * Nc + n) * Cc + c0ch) * CELLS;
        out[obase + tid]         = a0 * 0.125f;
        out[obase + CELLS + tid] = a1 * 0.125f;
    }
}

extern "C" void kernel_launch(void* const* d_in, const int* in_sizes, int n_in,
                              void* d_out, int out_size, void* d_ws, size_t ws_size,
                              hipStream_t stream) {
    const float* feat = (const float*)d_in[0];
    const float* rois = (const float*)d_in[1];
    float* out = (float*)d_out;
    hipLaunchKernelGGL(roialign3d_v17, dim3(Bc * Nc * (Cc / 2)), dim3(384), 0,
                       stream, feat, rois, out);
}

// Round 18
// 40.723 us; speedup vs baseline: 1.3118x; 1.3118x over previous
//
#include <hip/hip_runtime.h>

// ROIAlign3D: features [B=2,C=128,D=16,H=64,W=64] f32, rois [B,N=64,6] f32
// out [B,N,C,7,7,7] f32. SAMPLING_RATIO=2, ALIGNED=true, SPATIAL_SCALE=1.
//
// Round 18: REVERT to v15 verbatim (39.2us champion).
//  - v16 persistent grid: regressed (strided item map broke L2 box-union
//    reuse, FETCH 29->35MB; extra barrier serialized items).
//  - v17 n-fastest remap: regressed badly (FETCH 29->89MB: 64 concurrent ROI
//    boxes tile the whole plane -> full-volume refetch). cp-fastest order is
//    load-bearing for L2 reuse. MLP batching was ignored by compiler (VGPR
//    stayed 20) -- not actually tested.
// v15 = single kernel, single barrier; in-block 42-thread table build;
// packed-f16 broadcast weights; magic-div lane-consecutive staging with tight
// odd x-stride; z 3-slot collapse (12 gather points, 24 ds_read2/cell).
constexpr int Bc = 2, Nc = 64, Cc = 128, Dc = 16, Hc = 64, Wc = 64;
constexpr int OD = 7, OH = 7, OW = 7;
constexpr int CELLS = OD * OH * OW;          // 343
constexpr int DHW = Dc * Hc * Wc, HW = Hc * Wc;
constexpr int MAXZ = 10, MAXY = 25, MAXX = 25;
constexpr int SUBSZ = MAXZ * MAXY * (MAXX + 1);   // 6500

typedef _Float16 h2f __attribute__((ext_vector_type(2)));

__device__ inline unsigned pk_f16(float a, float b) {
    return __builtin_bit_cast(unsigned, __builtin_amdgcn_cvt_pkrtz(a, b));
}
__device__ inline h2f uh(unsigned u) { return __builtin_bit_cast(h2f, u); }

__global__ __launch_bounds__(384) void roialign3d_v18(
    const float* __restrict__ feat, const float* __restrict__ rois,
    float* __restrict__ out)
{
    __shared__ __align__(16) unsigned sub[SUBSZ + 2];
    __shared__ __align__(16) int2     tzp[14];   // raw z rows (c0,c1)
    __shared__ __align__(16) float2   wzp[14];
    __shared__ __align__(16) int2     typ[14];   // premult xnp
    __shared__ __align__(16) unsigned wyb[28];   // broadcast f16 pairs
    __shared__ __align__(16) unsigned wxb[28];
    __shared__ __align__(16) int      txo[14];

    const int blk = blockIdx.x;
    const int cp  = blk & 63;
    const int n   = (blk >> 6) & 63;
    const int b   = blk >> 12;
    const int tid = threadIdx.x;

    const float* rp = rois + (size_t)(b * Nc + n) * 6;
    float r1a[3] = {rp[0] - 0.5f, rp[1] - 0.5f, rp[2] - 0.5f};
    float r2a[3] = {rp[3] - 0.5f, rp[4] - 0.5f, rp[5] - 0.5f};
    const int dims[3] = {Dc, Hc, Wc};
    const int maxn[3] = {MAXZ, MAXY, MAXX};

    float bs[3]; int lo[3], ncnt[3];
    #pragma unroll
    for (int a = 0; a < 3; ++a) {
        bs[a] = fmaxf(r2a[a] - r1a[a], 1e-6f) * (1.0f / 7.0f);
        float smin = r1a[a] + 0.25f * bs[a];
        float smax = r1a[a] + 6.75f * bs[a];
        int l = max(0, (int)floorf(smin));
        int h = min(dims[a] - 1, (int)floorf(smax) + 1);
        lo[a] = l;
        ncnt[a] = min(h - l + 1, maxn[a]);    // maxn clamp = memory safety only
    }
    const int zn = ncnt[0], yn = ncnt[1], xn = ncnt[2];
    const int xnp = xn | 1;                   // odd stride (coprime w/ 32)
    const int rows = zn * yn;
    const int zstride = yn * xnp;

    // Axis tables (42 threads), packed-f16 broadcast weights for y/x.
    if (tid < 42) {
        int a = tid / 14, m = tid - a * 14;
        float v = r1a[a] + ((float)m + 0.5f) * 0.5f * bs[a];
        float f = floorf(v);
        float l = v - f;
        int i0 = (int)f;
        int d  = dims[a];
        float w0 = (i0 >= 0 && i0 < d) ? 1.0f - l : 0.0f;
        float w1 = (i0 + 1 < d) ? l : 0.0f;
        if (a == 0) {
            int c0 = min(max(i0 - lo[0], 0), zn - 1);
            int c1 = min(max(i0 + 1 - lo[0], 0), zn - 1);
            tzp[m] = make_int2(c0, c1);              // RAW rows
            wzp[m] = make_float2(w0, w1);
        } else if (a == 1) {
            int c0 = min(max(i0 - lo[1], 0), yn - 1);
            int c1 = min(max(i0 + 1 - lo[1], 0), yn - 1);
            typ[m] = make_int2(c0 * xnp, c1 * xnp);
            wyb[2 * m]     = pk_f16(w0, w0);
            wyb[2 * m + 1] = pk_f16(w1, w1);
        } else {
            // pair trick: corners are (c0, c0+1); c0 in [-1, xn-1].
            int c0 = min(max(i0 - lo[2], -1), xn - 1);
            txo[m] = c0;
            wxb[2 * m]     = pk_f16(w0, w0);
            wxb[2 * m + 1] = pk_f16(w1, w1);
        }
    }
    if (tid == 64) sub[0] = 0;                        // front pad (c0 = -1)
    if (tid == 65) sub[1 + rows * xnp] = 0;           // end pad

    // ---- Stage subvolume (fp16x2), lane-consecutive, magic-div. ----
    const int c0ch = cp * 2;
    const float* fb = feat + ((size_t)b * Cc + c0ch) * DHW;
    const unsigned m32x = 0xFFFFFFFFu / (unsigned)xnp + 1u;
    const unsigned m32y = 0xFFFFFFFFu / (unsigned)yn + 1u;
    const int gz = lo[0] * HW + lo[1] * Wc + lo[2];
    const int total = rows * xnp;
    for (int p = tid; p < total; p += 384) {
        int row = (int)__umulhi((unsigned)p, m32x);   // p / xnp
        int x   = p - row * xnp;
        int xs  = min(x, xn - 1);
        int z   = (int)__umulhi((unsigned)row, m32y); // row / yn
        int y   = row - z * yn;
        int g   = gz + (z << 12) + (y << 6) + xs;     // HW=4096, Wc=64
        sub[1 + p] = pk_f16(fb[g], fb[g + DHW]);
    }
    __syncthreads();

    if (tid < CELLS) {
        int i   = tid / 49;
        int rem = tid - i * 49;
        int j   = rem / 7;
        int k   = rem - j * 7;
        int4   tzr  = *(const int4*)&tzp[2 * i];    // (c0,c1,c0',c1') raw
        float4 wzv  = *(const float4*)&wzp[2 * i];
        int4   ty   = *(const int4*)&typ[2 * j];
        uint4  wyb4 = *(const uint4*)&wyb[4 * j];
        uint4  wxb4 = *(const uint4*)&wxb[4 * k];
        int xo0 = txo[2 * k], xo1 = txo[2 * k + 1];

        const unsigned* G = sub + 1;
        h2f wx00 = uh(wxb4.x), wx01 = uh(wxb4.y);
        h2f wx10 = uh(wxb4.z), wx11 = uh(wxb4.w);
        const h2f wys[4] = {uh(wyb4.x), uh(wyb4.y), uh(wyb4.z), uh(wyb4.w)};

        // z 3-slot collapse: corners lie in {c0, c0+1, c0+2}.
        int c0z = tzr.x;
        int p1 = tzr.y - c0z, p2 = tzr.z - c0z, p3 = tzr.w - c0z;
        float cz0 = wzv.x + (p1 == 0 ? wzv.y : 0.0f)
                  + (p2 == 0 ? wzv.z : 0.0f) + (p3 == 0 ? wzv.w : 0.0f);
        float cz1 = (p1 == 1 ? wzv.y : 0.0f)
                  + (p2 == 1 ? wzv.z : 0.0f) + (p3 == 1 ? wzv.w : 0.0f);
        float cz2 = (p3 == 2 ? wzv.w : 0.0f);
        int zb0 = c0z * zstride;
        int zb1 = min(c0z + 1, zn - 1) * zstride;
        int zb2 = min(c0z + 2, zn - 1) * zstride;

        const int   zbs[3] = {zb0, zb1, zb2};
        const float czs[3] = {cz0, cz1, cz2};
        const int   yo[4]  = {ty.x, ty.y, ty.z, ty.w};

        float a0 = 0.0f, a1 = 0.0f;
        #pragma unroll
        for (int d = 0; d < 3; ++d) {
            int zb = zbs[d];
            h2f s = {(_Float16)0, (_Float16)0};
            #pragma unroll
            for (int yi = 0; yi < 4; ++yi) {
                int base = zb + yo[yi];
                h2f A0 = uh(G[base + xo0]), A1 = uh(G[base + xo0 + 1]);
                h2f B0 = uh(G[base + xo1]), B1 = uh(G[base + xo1 + 1]);
                h2f xr = A0 * wx00 + A1 * wx01 + B0 * wx10 + B1 * wx11;
                s = s + wys[yi] * xr;
            }
            a0 = fmaf(czs[d], (float)s.x, a0);
            a1 = fmaf(czs[d], (float)s.y, a1);
        }
        size_t obase = ((size_t)(b * Nc + n) * Cc + c0ch) * CELLS;
        out[obase + tid]         = a0 * 0.125f;
        out[obase + CELLS + tid] = a1 * 0.125f;
    }
}

extern "C" void kernel_launch(void* const* d_in, const int* in_sizes, int n_in,
                              void* d_out, int out_size, void* d_ws, size_t ws_size,
                              hipStream_t stream) {
    const float* feat = (const float*)d_in[0];
    const float* rois = (const float*)d_in[1];
    float* out = (float*)d_out;
    hipLaunchKernelGGL(roialign3d_v18, dim3(Bc * Nc * (Cc / 2)), dim3(384), 0,
                       stream, feat, rois, out);
}